// Round 9
// baseline (272.940 us; speedup 1.0000x reference)
//
#include <hip/hip_runtime.h>
#include <math.h>

#define S_LEN 2048
#define HID   2048
#define NH    32
#define NKV   8
#define HD    64
#define BK    32

typedef short short4x __attribute__((ext_vector_type(4)));
typedef short short8  __attribute__((ext_vector_type(8)));
typedef float floatx4 __attribute__((ext_vector_type(4)));

static __device__ __forceinline__ ushort f2bf(float f) {
  unsigned u = __float_as_uint(f);
  u += 0x7fffu + ((u >> 16) & 1u);   // RNE; inputs finite
  return (ushort)(u >> 16);
}

// async global->LDS, 16B per lane; LDS dest = wave-uniform base + lane*16
static __device__ __forceinline__ void gl2lds16(const ushort* g, ushort* l) {
  __builtin_amdgcn_global_load_lds(
      (const __attribute__((address_space(1))) unsigned int*)g,
      (__attribute__((address_space(3))) unsigned int*)l, 16, 0, 0);
}

// ---------------- all fp32 -> bf16 conversions, one launch ----------------
#define QH  1048576
#define QW  1048576
#define QKq  262144
#define QVq  262144
#define QO  1048576
__global__ void cvt_all_kernel(const float* __restrict__ h,
                               const float* __restrict__ wq,
                               const float* __restrict__ wk,
                               const float* __restrict__ wv,
                               const float* __restrict__ wo,
                               ushort* __restrict__ hb,
                               ushort* __restrict__ wqkvb,
                               ushort* __restrict__ wob) {
  int idx = blockIdx.x * 256 + threadIdx.x;
  const float* src; ushort* dst; int so, dqo;
  if (idx < QH)                    { src = h;  dst = hb;    so = idx;                   dqo = so; }
  else if (idx < QH + QW)          { src = wq; dst = wqkvb; so = idx - QH;              dqo = so; }
  else if (idx < QH + QW + QKq)    { src = wk; dst = wqkvb; so = idx - QH - QW;         dqo = so + QW; }
  else if (idx < QH + QW + QKq + QVq) { src = wv; dst = wqkvb; so = idx - QH - QW - QKq; dqo = so + QW + QKq; }
  else                             { src = wo; dst = wob;   so = idx - QH - QW - QKq - QVq; dqo = so; }
  float4 v = ((const float4*)src)[so];
  ushort4 o;
  o.x = f2bf(v.x); o.y = f2bf(v.y); o.z = f2bf(v.z); o.w = f2bf(v.w);
  ((ushort4*)dst)[dqo] = o;
}

// ---- C[M][N] = A * B^T, 128(M)x64(N) tile, 4 waves (wave = 32Mx64N) ------
__global__ __launch_bounds__(256) void gemm64_bt_kernel(
    const ushort* __restrict__ A, const ushort* __restrict__ B,
    float* __restrict__ C, int M, int N, int K) {
  __shared__ __align__(16) ushort As[128 * BK];  // 8 KB
  __shared__ __align__(16) ushort Bs[64 * BK];   // 4 KB

  const int tid  = threadIdx.x;
  const int wave = tid >> 6;
  const int lane = tid & 63;
  const int r16  = lane & 15;
  const int quad = lane >> 4;

  const int m_base = blockIdx.y * 128;
  const int n_base = blockIdx.x * 64;
  const int wm = wave * 32;

  const int lrow = lane >> 2;          // 0..15
  const int scol = (lane & 3) * 8;
  const ushort* ag0 = A + (size_t)(m_base + wave * 32 + lrow) * K + scol;
  const ushort* ag1 = ag0 + (size_t)16 * K;
  const ushort* bg  = B + (size_t)(n_base + wave * 16 + lrow) * K + scol;
  ushort* as0 = As + (wave * 32) * BK;
  ushort* as1 = As + (wave * 32 + 16) * BK;
  ushort* bs  = Bs + (wave * 16) * BK;

  floatx4 acc[2][4];
#pragma unroll
  for (int i = 0; i < 2; ++i)
#pragma unroll
    for (int j = 0; j < 4; ++j) acc[i][j] = floatx4{0.f, 0.f, 0.f, 0.f};

  for (int kk = 0; kk < K; kk += BK) {
    __syncthreads();
    gl2lds16(ag0 + kk, as0);
    gl2lds16(ag1 + kk, as1);
    gl2lds16(bg + kk, bs);
    __syncthreads();

    short8 af[2], bf[4];
#pragma unroll
    for (int i = 0; i < 2; ++i)
      af[i] = *(const short8*)&As[(wm + i * 16 + r16) * BK + quad * 8];
#pragma unroll
    for (int j = 0; j < 4; ++j)
      bf[j] = *(const short8*)&Bs[(j * 16 + r16) * BK + quad * 8];
#pragma unroll
    for (int i = 0; i < 2; ++i)
#pragma unroll
      for (int j = 0; j < 4; ++j)
        acc[i][j] = __builtin_amdgcn_mfma_f32_16x16x32_bf16(af[i], bf[j], acc[i][j], 0, 0, 0);
  }

#pragma unroll
  for (int i = 0; i < 2; ++i)
#pragma unroll
    for (int j = 0; j < 4; ++j) {
      const int cm = m_base + wm + i * 16 + quad * 4;
      const int cn = n_base + j * 16 + r16;
#pragma unroll
      for (int r = 0; r < 4; ++r)
        C[(size_t)(cm + r) * N + cn] = acc[i][j][r];
    }
}

// ---- fused QKV GEMM (128x64 tile): epilogue RoPE + bf16 + layout ---------
// block's 64 cols = exactly one head.
__global__ __launch_bounds__(256) void gemm_qkv_kernel(
    const ushort* __restrict__ A, const ushort* __restrict__ B,
    const int* __restrict__ pos,
    ushort* __restrict__ qr,    // [NH][S][64]  bf16 roped
    ushort* __restrict__ kr,    // [NKV][S][64] bf16 roped
    ushort* __restrict__ vtb) { // [NKV][64][S] bf16
  __shared__ __align__(16) ushort As[128 * BK];
  __shared__ __align__(16) ushort Bs[64 * BK];

  const int K = HID;
  const int tid  = threadIdx.x;
  const int wave = tid >> 6;
  const int lane = tid & 63;
  const int r16  = lane & 15;
  const int quad = lane >> 4;

  const int m_base = blockIdx.y * 128;
  const int n_base = blockIdx.x * 64;
  const int wm = wave * 32;

  const int lrow = lane >> 2;
  const int scol = (lane & 3) * 8;
  const ushort* ag0 = A + (size_t)(m_base + wave * 32 + lrow) * K + scol;
  const ushort* ag1 = ag0 + (size_t)16 * K;
  const ushort* bg  = B + (size_t)(n_base + wave * 16 + lrow) * K + scol;
  ushort* as0 = As + (wave * 32) * BK;
  ushort* as1 = As + (wave * 32 + 16) * BK;
  ushort* bs  = Bs + (wave * 16) * BK;

  floatx4 acc[2][4];
#pragma unroll
  for (int i = 0; i < 2; ++i)
#pragma unroll
    for (int j = 0; j < 4; ++j) acc[i][j] = floatx4{0.f, 0.f, 0.f, 0.f};

  for (int kk = 0; kk < K; kk += BK) {
    __syncthreads();
    gl2lds16(ag0 + kk, as0);
    gl2lds16(ag1 + kk, as1);
    gl2lds16(bg + kk, bs);
    __syncthreads();

    short8 af[2], bf[4];
#pragma unroll
    for (int i = 0; i < 2; ++i)
      af[i] = *(const short8*)&As[(wm + i * 16 + r16) * BK + quad * 8];
#pragma unroll
    for (int j = 0; j < 4; ++j)
      bf[j] = *(const short8*)&Bs[(j * 16 + r16) * BK + quad * 8];
#pragma unroll
    for (int i = 0; i < 2; ++i)
#pragma unroll
      for (int j = 0; j < 4; ++j)
        acc[i][j] = __builtin_amdgcn_mfma_f32_16x16x32_bf16(af[i], bf[j], acc[i][j], 0, 0, 0);
  }

  const int n0 = n_base;   // head base (wave-uniform)
  if (n0 < HID + NKV * HD) {
    ushort* dst;
    if (n0 < HID) dst = qr + (size_t)(n0 >> 6) * S_LEN * 64;
    else          dst = kr + (size_t)((n0 - HID) >> 6) * S_LEN * 64;
    const float invfA = powf(10000.0f, -(float)r16 * (1.0f / 32.0f));
    const float invfB = powf(10000.0f, -(float)(16 + r16) * (1.0f / 32.0f));
#pragma unroll
    for (int i = 0; i < 2; ++i) {
#pragma unroll
      for (int r = 0; r < 4; ++r) {
        const int s = m_base + wm + i * 16 + quad * 4 + r;
        const float p = (float)pos[s];
        float snA, csA, snB, csB;
        sincosf(p * invfA, &snA, &csA);
        sincosf(p * invfB, &snB, &csB);
        ushort* row = dst + (size_t)s * 64;
        row[r16]      = f2bf(acc[i][0][r] * csA - acc[i][2][r] * snA);
        row[16 + r16] = f2bf(acc[i][1][r] * csB - acc[i][3][r] * snB);
        row[32 + r16] = f2bf(acc[i][2][r] * csA + acc[i][0][r] * snA);
        row[48 + r16] = f2bf(acc[i][3][r] * csB + acc[i][1][r] * snB);
      }
    }
  } else {
    const int hh = (n0 - HID - NKV * HD) >> 6;
#pragma unroll
    for (int i = 0; i < 2; ++i) {
      const int s0 = m_base + wm + i * 16 + quad * 4;
#pragma unroll
      for (int j = 0; j < 4; ++j) {
        const int d = j * 16 + r16;
        ushort4 o4;
        o4.x = f2bf(acc[i][j][0]);
        o4.y = f2bf(acc[i][j][1]);
        o4.z = f2bf(acc[i][j][2]);
        o4.w = f2bf(acc[i][j][3]);
        *(ushort4*)&vtb[((size_t)hh * 64 + d) * S_LEN + s0] = o4;
      }
    }
  }
}

// ---------------- causal GQA flash attention (MFMA bf16) ------------------
// 128-q blocks, 32 q per wave (two 16-q groups sharing K/V fragments).
// Static max (m = 16 in base-2 domain) -> no online rescale; l deferred.
#define LOG2E_SC 0.180336880f   // (1/sqrt(64)) * log2(e)
#define MSTAT    16.0f

__global__ __launch_bounds__(256) void attn_kernel(
    const ushort* __restrict__ Q,   // [NH][S][64]  bf16 roped
    const ushort* __restrict__ K,   // [NKV][S][64] bf16 roped
    const ushort* __restrict__ Vt,  // [NKV][64][S] bf16
    ushort* __restrict__ O) {       // [S][NH*64]   bf16
  __shared__ __align__(16) ushort Ks[64][72];
  __shared__ __align__(16) ushort Vs[64][72];
  __shared__ __align__(16) ushort Pw[4][32][72];   // per-wave P [q (2 groups)][key]

  const int h    = blockIdx.x;
  const int kh   = h >> 2;                         // GROUPS = 4
  const int y    = blockIdx.y;
  const int qt   = (y & 1) ? (15 - (y >> 1)) : (y >> 1);  // load balance
  const int tid  = threadIdx.x;
  const int wave = tid >> 6;
  const int lane = tid & 63;
  const int r16  = lane & 15;
  const int quad = lane >> 4;

  const int base = qt * 128 + wave * 32;           // wave's first query

  const ushort* qpA = Q + ((size_t)h * S_LEN + base + r16) * 64 + quad * 8;
  const short8 qfA0 = *(const short8*)(qpA);
  const short8 qfA1 = *(const short8*)(qpA + 32);
  const ushort* qpB = qpA + (size_t)16 * 64;
  const short8 qfB0 = *(const short8*)(qpB);
  const short8 qfB1 = *(const short8*)(qpB + 32);

  float lA = 0.f, lB = 0.f;
  floatx4 oaccA[4], oaccB[4];
#pragma unroll
  for (int n = 0; n < 4; ++n) {
    oaccA[n] = floatx4{0.f, 0.f, 0.f, 0.f};
    oaccB[n] = floatx4{0.f, 0.f, 0.f, 0.f};
  }

  const int ntile = 2 * qt + 2;
  for (int kt = 0; kt < ntile; ++kt) {
    __syncthreads();
    {
      const ushort* ksrc = K  + ((size_t)kh * S_LEN + kt * 64) * 64;
      const ushort* vsrc = Vt + ((size_t)kh * 64) * S_LEN + kt * 64;
#pragma unroll
      for (int i = tid; i < 512; i += 256) {
        int r = i >> 3, c = (i & 7) * 8;
        *(short8*)&Ks[r][c] = *(const short8*)(ksrc + (size_t)r * 64 + c);
        *(short8*)&Vs[r][c] = *(const short8*)(vsrc + (size_t)r * S_LEN + c);
      }
    }
    __syncthreads();

    if (kt * 64 > base + 31) continue;   // wave fully masked (wave-uniform)

    // ---- scores transposed, K-frags shared across both q-groups ----
    floatx4 sA[4], sB[4];
#pragma unroll
    for (int t = 0; t < 4; ++t) {
      short8 kf0 = *(const short8*)&Ks[t * 16 + r16][quad * 8];
      short8 kf1 = *(const short8*)&Ks[t * 16 + r16][32 + quad * 8];
      floatx4 z;
      z = floatx4{0.f, 0.f, 0.f, 0.f};
      z = __builtin_amdgcn_mfma_f32_16x16x32_bf16(kf0, qfA0, z, 0, 0, 0);
      sA[t] = __builtin_amdgcn_mfma_f32_16x16x32_bf16(kf1, qfA1, z, 0, 0, 0);
      z = floatx4{0.f, 0.f, 0.f, 0.f};
      z = __builtin_amdgcn_mfma_f32_16x16x32_bf16(kf0, qfB0, z, 0, 0, 0);
      sB[t] = __builtin_amdgcn_mfma_f32_16x16x32_bf16(kf1, qfB1, z, 0, 0, 0);
    }

    // ---- softmax (static max), per group ----
    const int key0 = kt * 64 + quad * 4;
#pragma unroll
    for (int g = 0; g < 2; ++g) {
      floatx4* s = g ? sB : sA;
      const int qg = base + g * 16 + r16;
      const bool maskN = (kt * 64 + 63 > base + g * 16);  // wave-uniform
      float ps = 0.f;
#pragma unroll
      for (int t = 0; t < 4; ++t) {
        float p[4];
#pragma unroll
        for (int r = 0; r < 4; ++r) {
          float sc = s[t][r] * LOG2E_SC - MSTAT;
          if (maskN && (key0 + t * 16 + r) > qg) sc = -1e30f;
          p[r] = __builtin_amdgcn_exp2f(sc);
        }
        ps += (p[0] + p[1]) + (p[2] + p[3]);
        *(short4x*)&Pw[wave][g * 16 + r16][t * 16 + quad * 4] =
            short4x{(short)f2bf(p[0]), (short)f2bf(p[1]),
                    (short)f2bf(p[2]), (short)f2bf(p[3])};
      }
      if (g) lB += ps; else lA += ps;
    }

    // ---- PV: V-frags shared across both q-groups ----
    short8 pA0 = *(const short8*)&Pw[wave][r16][quad * 8];
    short8 pA1 = *(const short8*)&Pw[wave][r16][32 + quad * 8];
    short8 pB0 = *(const short8*)&Pw[wave][16 + r16][quad * 8];
    short8 pB1 = *(const short8*)&Pw[wave][16 + r16][32 + quad * 8];
#pragma unroll
    for (int n = 0; n < 4; ++n) {
      short8 vf0 = *(const short8*)&Vs[n * 16 + r16][quad * 8];
      short8 vf1 = *(const short8*)&Vs[n * 16 + r16][32 + quad * 8];
      oaccA[n] = __builtin_amdgcn_mfma_f32_16x16x32_bf16(vf0, pA0, oaccA[n], 0, 0, 0);
      oaccA[n] = __builtin_amdgcn_mfma_f32_16x16x32_bf16(vf1, pA1, oaccA[n], 0, 0, 0);
      oaccB[n] = __builtin_amdgcn_mfma_f32_16x16x32_bf16(vf0, pB0, oaccB[n], 0, 0, 0);
      oaccB[n] = __builtin_amdgcn_mfma_f32_16x16x32_bf16(vf1, pB1, oaccB[n], 0, 0, 0);
    }
  }

  // ---- epilogue: reduce l across quads, normalize, store ----
  lA += __shfl_xor(lA, 16); lA += __shfl_xor(lA, 32);
  lB += __shfl_xor(lB, 16); lB += __shfl_xor(lB, 32);
  const float invA = 1.f / lA;
  const float invB = 1.f / lB;
  const int qA = base + r16;
  const int qB = base + 16 + r16;
#pragma unroll
  for (int n = 0; n < 4; ++n) {
    ushort4 oa, ob2;
    oa.x = f2bf(oaccA[n][0] * invA); oa.y = f2bf(oaccA[n][1] * invA);
    oa.z = f2bf(oaccA[n][2] * invA); oa.w = f2bf(oaccA[n][3] * invA);
    ob2.x = f2bf(oaccB[n][0] * invB); ob2.y = f2bf(oaccB[n][1] * invB);
    ob2.z = f2bf(oaccB[n][2] * invB); ob2.w = f2bf(oaccB[n][3] * invB);
    *(ushort4*)&O[(size_t)qA * (NH * HD) + h * 64 + n * 16 + quad * 4] = oa;
    *(ushort4*)&O[(size_t)qB * (NH * HD) + h * 64 + n * 16 + quad * 4] = ob2;
  }
}

// --------------------------------------------------------------------------
extern "C" void kernel_launch(void* const* d_in, const int* in_sizes, int n_in,
                              void* d_out, int out_size, void* d_ws, size_t ws_size,
                              hipStream_t stream) {
  const float* hidden = (const float*)d_in[0];
  const int*   pos    = (const int*)d_in[2];
  const float* Wq     = (const float*)d_in[3];
  const float* Wk     = (const float*)d_in[4];
  const float* Wv     = (const float*)d_in[5];
  const float* Wo     = (const float*)d_in[6];
  float* out = (float*)d_out;

  const int NQKV = HID + 2 * NKV * HD;  // 3072

  char* w = (char*)d_ws;
  auto carve = [&](size_t bytes) { char* p = w; w += bytes; return p; };
  ushort* hb    = (ushort*)carve((size_t)S_LEN * HID * 2);
  ushort* wqkvb = (ushort*)carve((size_t)NQKV * HID * 2);
  ushort* wob   = (ushort*)carve((size_t)HID * HID * 2);
  ushort* qr    = (ushort*)carve((size_t)NH * S_LEN * HD * 2);
  ushort* kr    = (ushort*)carve((size_t)NKV * S_LEN * HD * 2);
  ushort* vtb   = (ushort*)carve((size_t)NKV * HD * S_LEN * 2);
  ushort* ob    = (ushort*)carve((size_t)S_LEN * HID * 2);

  // 1) all bf16 conversions, one launch
  cvt_all_kernel<<<(QH + QW + QKq + QVq + QO) / 256, 256, 0, stream>>>(
      hidden, Wq, Wk, Wv, Wo, hb, wqkvb, wob);

  // 2) fused QKV projection + RoPE + layout epilogue (128x64 tiles)
  dim3 gqkv(NQKV / 64, S_LEN / 128);
  gemm_qkv_kernel<<<gqkv, 256, 0, stream>>>(hb, wqkvb, pos, qr, kr, vtb);

  // 3) causal GQA attention (MFMA, 128-q blocks) -> bf16 [S][NH*HD]
  dim3 ga(NH, S_LEN / 128);
  attn_kernel<<<ga, 256, 0, stream>>>(qr, kr, vtb, ob);

  // 4) output projection (128x64 tiles) -> fp32 d_out
  dim3 go(HID / 64, S_LEN / 128);
  gemm64_bt_kernel<<<go, 256, 0, stream>>>(ob, wob, out, S_LEN, HID, HID);
}